// Round 6
// baseline (201.001 us; speedup 1.0000x reference)
//
#include <hip/hip_runtime.h>

typedef __attribute__((ext_vector_type(8))) short short8;
typedef __attribute__((ext_vector_type(4))) short short4v;
typedef __attribute__((ext_vector_type(4))) float floatx4;

__device__ inline ushort f2b(float f) {
    union { uint i; float f; } c; c.f = f;
    uint i = c.i;
    uint r = (i + 0x7FFFu + ((i >> 16) & 1u)) >> 16;
    return (ushort)r;
}

__device__ __forceinline__ void load_lds16(const ushort* g, ushort* l) {
    __builtin_amdgcn_global_load_lds((const __attribute__((address_space(1))) void*)g,
                                     (__attribute__((address_space(3))) void*)l, 16, 0, 0);
}

// Fused fp32->bf16 conversion of x, wq, wk, wv + RoPE cos/sin table (one launch).
__global__ __launch_bounds__(256) void cvt4_k(const float* __restrict__ x,
                                              const float* __restrict__ wq,
                                              const float* __restrict__ wk,
                                              const float* __restrict__ wv,
                                              ushort* __restrict__ xb,
                                              ushort* __restrict__ wqb,
                                              ushort* __restrict__ wkb,
                                              ushort* __restrict__ wvb,
                                              const int* __restrict__ pos,
                                              float2* __restrict__ tab) {
    const int blk = blockIdx.x;
    if (blk >= 3584) {
        const int idx = (blk - 3584) * 256 + threadIdx.x;   // 0..65535
        const int s = idx >> 5, fi = idx & 31;
        const float inv = exp2f(-(float)fi * 0.41524101186092557f);
        const float ang = (float)pos[s] * inv;
        float sn, cs;
        sincosf(ang, &sn, &cs);
        tab[idx] = make_float2(cs, sn);
        return;
    }
    const float* in; ushort* out; int base;
    if (blk < 2048)      { in = x;  out = xb;  base = blk; }
    else if (blk < 2560) { in = wq; out = wqb; base = blk - 2048; }
    else if (blk < 3072) { in = wk; out = wkb; base = blk - 2560; }
    else                 { in = wv; out = wvb; base = blk - 3072; }
    const int i = (base * 256 + threadIdx.x) * 8;
    float4 f0 = *(const float4*)(in + i);
    float4 f1 = *(const float4*)(in + i + 4);
    ushort u[8] = {f2b(f0.x), f2b(f0.y), f2b(f0.z), f2b(f0.w),
                   f2b(f1.x), f2b(f1.y), f2b(f1.z), f2b(f1.w)};
    *(uint4*)(out + i) = *(const uint4*)u;
}

__global__ __launch_bounds__(256) void cvt_k(const float* __restrict__ in,
                                             ushort* __restrict__ out, int n) {
    const int i = (blockIdx.x * 256 + threadIdx.x) * 8;
    if (i >= n) return;
    float4 f0 = *(const float4*)(in + i);
    float4 f1 = *(const float4*)(in + i + 4);
    ushort u[8] = {f2b(f0.x), f2b(f0.y), f2b(f0.z), f2b(f0.w),
                   f2b(f1.x), f2b(f1.y), f2b(f1.z), f2b(f1.w)};
    *(uint4*)(out + i) = *(const uint4*)u;
}

// 128x128 GEMM body, K=1024, BK=32, 4 waves (2x2 of 64x64).
// Verified 2-phase structure: double-buffered LDS, one __syncthreads per
// K-iter; prefetch of tile kt+1 overlaps compute of tile kt.
template <bool OUTF32>
__device__ __forceinline__ void gemm_body(ushort* As, ushort* Bs,   // [2][4096] each
                                          const ushort* __restrict__ A,
                                          const ushort* __restrict__ B,
                                          void* __restrict__ C,
                                          int N, int m0, int n0,
                                          bool doRope, const float2* __restrict__ tab,
                                          float oscale) {
    const int tid = threadIdx.x;
    const int wave = tid >> 6, lane = tid & 63;
    const int quad = lane >> 4, l16 = lane & 15;
    const int wm = (wave >> 1) * 64, wn = (wave & 1) * 64;

    floatx4 acc[4][4] = {};

    const int cA = tid, cB = tid + 256;
    const int rA = cA >> 2, jgA = ((cA & 3) - (rA >> 1)) & 3;
    const int rB = cB >> 2, jgB = ((cB & 3) - (rB >> 1)) & 3;
    const ushort* gaA = A + (size_t)(m0 + rA) * 1024 + jgA * 8;
    const ushort* gaB = A + (size_t)(m0 + rB) * 1024 + jgB * 8;
    const ushort* gbA = B + (size_t)(n0 + rA) * 1024 + jgA * 8;
    const ushort* gbB = B + (size_t)(n0 + rB) * 1024 + jgB * 8;

    load_lds16(gaA, As + cA * 8);
    load_lds16(gaB, As + cB * 8);
    load_lds16(gbA, Bs + cA * 8);
    load_lds16(gbB, Bs + cB * 8);
    __syncthreads();

    for (int kt = 0; kt < 32; ++kt) {
        const int cur = kt & 1;
        if (kt + 1 < 32) {
            const int nb = (cur ^ 1) * 4096;
            load_lds16(gaA + (kt + 1) * 32, As + nb + cA * 8);
            load_lds16(gaB + (kt + 1) * 32, As + nb + cB * 8);
            load_lds16(gbA + (kt + 1) * 32, Bs + nb + cA * 8);
            load_lds16(gbB + (kt + 1) * 32, Bs + nb + cB * 8);
        }
        const ushort* as = As + cur * 4096;
        const ushort* bs = Bs + cur * 4096;
        short8 af[4], bf[4];
#pragma unroll
        for (int i = 0; i < 4; ++i) {
            const int ra = wm + i * 16 + l16;
            const int rb = wn + i * 16 + l16;
            af[i] = *(const short8*)(as + ra * 32 + (((quad + (ra >> 1)) & 3) << 3));
            bf[i] = *(const short8*)(bs + rb * 32 + (((quad + (rb >> 1)) & 3) << 3));
        }
#pragma unroll
        for (int mi = 0; mi < 4; ++mi)
#pragma unroll
            for (int ni = 0; ni < 4; ++ni)
                acc[mi][ni] = __builtin_amdgcn_mfma_f32_16x16x32_bf16(af[mi], bf[ni], acc[mi][ni], 0, 0, 0);
        __syncthreads();
    }
#pragma unroll
    for (int mi = 0; mi < 4; ++mi) {
        const int row = m0 + wm + mi * 16 + quad * 4;
#pragma unroll
        for (int ni = 0; ni < 4; ++ni) {
            const int col = n0 + wn + ni * 16 + l16;
            const int fi = ((wn + ni * 16 + l16) & 63) >> 1;
#pragma unroll
            for (int r = 0; r < 4; ++r) {
                float v = acc[mi][ni][r];
                if (doRope) {
                    const float other = __shfl_xor(v, 1);
                    const float2 cs = tab[((row + r) & 2047) * 32 + fi];
                    v = (col & 1) ? (other * cs.y + v * cs.x) : (v * cs.x - other * cs.y);
                }
                v *= oscale;
                if (OUTF32) ((float*)C)[(size_t)(row + r) * N + col] = v;
                else        ((ushort*)C)[(size_t)(row + r) * N + col] = f2b(v);
            }
        }
    }
}

// Fused Q+K / Vt GEMM, 512 blocks (2/CU).
// Blocks [0,256): ONE block computes both the Q-tile and K-tile at (m0,n0),
//   staging the shared A-panel (xb) ONCE: staged bytes 32->24 KB per iter-pair,
//   LDS reads 16->12 per wave. Same verified 2-phase sync skeleton.
// Blocks [256,512): Vt job via gemm_body (unchanged).
__global__ __launch_bounds__(256, 2) void gemm_qkv(const ushort* __restrict__ xb,
                                                   const ushort* __restrict__ wqb,
                                                   const ushort* __restrict__ wkb,
                                                   const ushort* __restrict__ wvb,
                                                   ushort* __restrict__ q,
                                                   ushort* __restrict__ k,
                                                   ushort* __restrict__ vt,
                                                   const float2* __restrict__ tab) {
    __shared__ __align__(16) ushort As[8192], Bqs[8192], Bks[8192];   // 48 KB
    const int blk = blockIdx.x;
    if (blk >= 256) {   // Vt: vt[1024][4096] = wvb * xb^T
        const int r = blk - 256;
        gemm_body<false>(As, Bqs, wvb, xb, vt, 4096, (r & 7) * 128, (r >> 3) * 128,
                         false, tab, 1.0f);
        return;
    }
    const int tid = threadIdx.x;
    const int wave = tid >> 6, lane = tid & 63;
    const int quad = lane >> 4, l16 = lane & 15;
    const int wm = (wave >> 1) * 64, wn = (wave & 1) * 64;
    const int m0 = (blk >> 3) * 128, n0 = (blk & 7) * 128;

    floatx4 aq[4][4] = {}, ak[4][4] = {};

    const int cA = tid, cB = tid + 256;
    const int rA = cA >> 2, jgA = ((cA & 3) - (rA >> 1)) & 3;
    const int rB = cB >> 2, jgB = ((cB & 3) - (rB >> 1)) & 3;
    const ushort* gaA = xb  + (size_t)(m0 + rA) * 1024 + jgA * 8;
    const ushort* gaB = xb  + (size_t)(m0 + rB) * 1024 + jgB * 8;
    const ushort* gqA = wqb + (size_t)(n0 + rA) * 1024 + jgA * 8;
    const ushort* gqB = wqb + (size_t)(n0 + rB) * 1024 + jgB * 8;
    const ushort* gkA = wkb + (size_t)(n0 + rA) * 1024 + jgA * 8;
    const ushort* gkB = wkb + (size_t)(n0 + rB) * 1024 + jgB * 8;

    load_lds16(gaA, As + cA * 8);
    load_lds16(gaB, As + cB * 8);
    load_lds16(gqA, Bqs + cA * 8);
    load_lds16(gqB, Bqs + cB * 8);
    load_lds16(gkA, Bks + cA * 8);
    load_lds16(gkB, Bks + cB * 8);
    __syncthreads();

    for (int kt = 0; kt < 32; ++kt) {
        const int cur = kt & 1;
        if (kt + 1 < 32) {
            const int nb = (cur ^ 1) * 4096;
            load_lds16(gaA + (kt + 1) * 32, As + nb + cA * 8);
            load_lds16(gaB + (kt + 1) * 32, As + nb + cB * 8);
            load_lds16(gqA + (kt + 1) * 32, Bqs + nb + cA * 8);
            load_lds16(gqB + (kt + 1) * 32, Bqs + nb + cB * 8);
            load_lds16(gkA + (kt + 1) * 32, Bks + nb + cA * 8);
            load_lds16(gkB + (kt + 1) * 32, Bks + nb + cB * 8);
        }
        const ushort* as = As + cur * 4096;
        const ushort* qs = Bqs + cur * 4096;
        const ushort* ks = Bks + cur * 4096;
        short8 af[4], bq[4], bk[4];
#pragma unroll
        for (int i = 0; i < 4; ++i) {
            const int ra = wm + i * 16 + l16;
            const int rb = wn + i * 16 + l16;
            const int sa = ra * 32 + (((quad + (ra >> 1)) & 3) << 3);
            const int sb = rb * 32 + (((quad + (rb >> 1)) & 3) << 3);
            af[i] = *(const short8*)(as + sa);
            bq[i] = *(const short8*)(qs + sb);
            bk[i] = *(const short8*)(ks + sb);
        }
#pragma unroll
        for (int mi = 0; mi < 4; ++mi)
#pragma unroll
            for (int ni = 0; ni < 4; ++ni) {
                aq[mi][ni] = __builtin_amdgcn_mfma_f32_16x16x32_bf16(af[mi], bq[ni], aq[mi][ni], 0, 0, 0);
                ak[mi][ni] = __builtin_amdgcn_mfma_f32_16x16x32_bf16(af[mi], bk[ni], ak[mi][ni], 0, 0, 0);
            }
        __syncthreads();
    }

    // RoPE epilogue for both Q (softmax scale folded) and K; shared tab load.
    const float SCL = 0.18033688011112042f;        // 0.125 * log2(e)
#pragma unroll
    for (int mi = 0; mi < 4; ++mi) {
        const int row = m0 + wm + mi * 16 + quad * 4;
#pragma unroll
        for (int ni = 0; ni < 4; ++ni) {
            const int col = n0 + wn + ni * 16 + l16;
            const int fi = ((wn + ni * 16 + l16) & 63) >> 1;
#pragma unroll
            for (int r = 0; r < 4; ++r) {
                const float2 cs = tab[((row + r) & 2047) * 32 + fi];
                float vq = aq[mi][ni][r];
                float oq = __shfl_xor(vq, 1);
                vq = (col & 1) ? (oq * cs.y + vq * cs.x) : (vq * cs.x - oq * cs.y);
                q[(size_t)(row + r) * 1024 + col] = f2b(vq * SCL);
                float vk = ak[mi][ni][r];
                float ok = __shfl_xor(vk, 1);
                vk = (col & 1) ? (ok * cs.y + vk * cs.x) : (vk * cs.x - ok * cs.y);
                k[(size_t)(row + r) * 1024 + col] = f2b(vk);
            }
        }
    }
}

// Output projection: C fp32 = O[4096][1024] * wo[1024][1024]^T.
// R4-verified form: 128x64 tiles, 512 blocks = 2 blocks/CU, bf16 B via cvt_k.
__global__ __launch_bounds__(256) void gemm_o(const ushort* __restrict__ A,
                                              const ushort* __restrict__ B,
                                              float* __restrict__ C) {
    __shared__ __align__(16) ushort As[8192];   // 2 bufs x 128 rows x 32 cols
    __shared__ __align__(16) ushort Bs[4096];   // 2 bufs x  64 rows x 32 cols

    const int blk = blockIdx.x;
    const int m0 = (blk >> 4) * 128, n0 = (blk & 15) * 64;

    const int tid = threadIdx.x;
    const int wave = tid >> 6, lane = tid & 63;
    const int quad = lane >> 4, l16 = lane & 15;
    const int wm = (wave >> 1) * 64, wn = (wave & 1) * 32;

    floatx4 acc[4][2] = {};

    const int cA1 = tid, cA2 = tid + 256, cBc = tid;
    const int rA1 = cA1 >> 2, jg1 = ((cA1 & 3) - (rA1 >> 1)) & 3;
    const int rA2 = cA2 >> 2, jg2 = ((cA2 & 3) - (rA2 >> 1)) & 3;
    const int rBc = cBc >> 2, jgB = ((cBc & 3) - (rBc >> 1)) & 3;
    const ushort* ga1 = A + (size_t)(m0 + rA1) * 1024 + jg1 * 8;
    const ushort* ga2 = A + (size_t)(m0 + rA2) * 1024 + jg2 * 8;
    const ushort* gb1 = B + (size_t)(n0 + rBc) * 1024 + jgB * 8;

    load_lds16(ga1, As + cA1 * 8);
    load_lds16(ga2, As + cA2 * 8);
    load_lds16(gb1, Bs + cBc * 8);
    __syncthreads();

    for (int kt = 0; kt < 32; ++kt) {
        const int cur = kt & 1;
        if (kt + 1 < 32) {
            const int nbA = (cur ^ 1) * 4096;
            const int nbB = (cur ^ 1) * 2048;
            load_lds16(ga1 + (kt + 1) * 32, As + nbA + cA1 * 8);
            load_lds16(ga2 + (kt + 1) * 32, As + nbA + cA2 * 8);
            load_lds16(gb1 + (kt + 1) * 32, Bs + nbB + cBc * 8);
        }
        const ushort* as = As + cur * 4096;
        const ushort* bs = Bs + cur * 2048;
        short8 af[4], bf[2];
#pragma unroll
        for (int i = 0; i < 4; ++i) {
            const int ra = wm + i * 16 + l16;
            af[i] = *(const short8*)(as + ra * 32 + (((quad + (ra >> 1)) & 3) << 3));
        }
#pragma unroll
        for (int j = 0; j < 2; ++j) {
            const int rb = wn + j * 16 + l16;
            bf[j] = *(const short8*)(bs + rb * 32 + (((quad + (rb >> 1)) & 3) << 3));
        }
#pragma unroll
        for (int mi = 0; mi < 4; ++mi)
#pragma unroll
            for (int ni = 0; ni < 2; ++ni)
                acc[mi][ni] = __builtin_amdgcn_mfma_f32_16x16x32_bf16(af[mi], bf[ni], acc[mi][ni], 0, 0, 0);
        __syncthreads();
    }
#pragma unroll
    for (int mi = 0; mi < 4; ++mi) {
        const int row = m0 + wm + mi * 16 + quad * 4;
#pragma unroll
        for (int ni = 0; ni < 2; ++ni) {
            const int col = n0 + wn + ni * 16 + l16;
#pragma unroll
            for (int r = 0; r < 4; ++r)
                C[(size_t)(row + r) * 1024 + col] = acc[mi][ni][r];
        }
    }
}

// Causal flash attention. 1024 blocks: one 64-row q-tile each, heavy tiles
// first; 4 blocks/CU. Q pre-scaled by 0.125*log2(e), so P = exp2(S) directly.
// Diagonal k-tile peeled (maskless main loop). Verified structure.
__global__ __launch_bounds__(256, 4) void attn_k(const ushort* __restrict__ Qg,
                                                 const ushort* __restrict__ Kg,
                                                 const ushort* __restrict__ Vtg,
                                                 ushort* __restrict__ Og) {
    __shared__ __align__(16) ushort Ks[2][4096];   // [s][d] chunk-swizzled
    __shared__ __align__(16) ushort Vs[2][4096];   // [d][s] chunk-swizzled

    const int tid = threadIdx.x;
    const int wave = tid >> 6, lane = tid & 63;
    const int quad = lane >> 4, l16 = lane & 15;
    const int blk = blockIdx.x;
    const int bh = blk & 31;
    const int qt = 31 - (blk >> 5);                // heavy-first
    const int b = bh >> 4, h = bh & 15;
    const int bq = b * 2048;
    const int wl = wave * 16 + l16;                // q-row within 64-row tile
    const int nk = qt + 1, dt = nk - 1;

    const int cA = tid, cB = tid + 256;
    const int sA = cA >> 3, jA = ((cA & 7) - sA) & 7;
    const int sB = cB >> 3, jB = ((cB & 7) - sB) & 7;
    const ushort* kgA = Kg + (size_t)(bq + sA) * 1024 + h * 64 + jA * 8;
    const ushort* kgB = Kg + (size_t)(bq + sB) * 1024 + h * 64 + jB * 8;
    const ushort* vgA = Vtg + (size_t)(h * 64 + sA) * 4096 + bq + jA * 8;
    const ushort* vgB = Vtg + (size_t)(h * 64 + sB) * 4096 + bq + jB * 8;

    // kt-invariant LDS read offsets (ushort units)
    const int kb0 = l16 * 64 + (((quad + l16) & 7) << 3);
    const int kb1 = l16 * 64 + (((quad + 4 + l16) & 7) << 3);
    int vbs[4];
#pragma unroll
    for (int cb = 0; cb < 4; ++cb)
        vbs[cb] = l16 * 64 + (((cb * 2 + (quad >> 1) + l16) & 7) << 3) + (quad & 1) * 4;

    const ushort* qrow = Qg + (size_t)(bq + qt * 64 + wl) * 1024 + h * 64 + quad * 8;
    const short8 qf0 = *(const short8*)qrow;
    const short8 qf1 = *(const short8*)(qrow + 32);

    floatx4 od[4] = {};
    float l_st = 0.0f;

    load_lds16(kgA, &Ks[0][cA * 8]);
    load_lds16(kgB, &Ks[0][cB * 8]);
    load_lds16(vgA, &Vs[0][cA * 8]);
    load_lds16(vgB, &Vs[0][cB * 8]);
    __syncthreads();

    const ushort* kgA2 = kgA + 65536;
    const ushort* kgB2 = kgB + 65536;
    const ushort* vgA2 = vgA + 64;
    const ushort* vgB2 = vgB + 64;

    auto step = [&](int kt, bool diag, bool pref) {
        const int cur = kt & 1;
        if (pref) {
            const int nxt = cur ^ 1;
            load_lds16(kgA2, &Ks[nxt][cA * 8]);
            load_lds16(kgB2, &Ks[nxt][cB * 8]);
            load_lds16(vgA2, &Vs[nxt][cA * 8]);
            load_lds16(vgB2, &Vs[nxt][cB * 8]);
            kgA2 += 65536; kgB2 += 65536; vgA2 += 64; vgB2 += 64;
        }
        const ushort* kc = &Ks[cur][0];
        const ushort* vc = &Vs[cur][0];

        // S^T = K Q^T  (Q pre-scaled, st already in log2 domain)
        floatx4 st[4];
        __builtin_amdgcn_s_setprio(1);
#pragma unroll
        for (int cb = 0; cb < 4; ++cb) {
            short8 kf0 = *(const short8*)(kc + kb0 + cb * 1024);
            short8 kf1 = *(const short8*)(kc + kb1 + cb * 1024);
            floatx4 z = {};
            z = __builtin_amdgcn_mfma_f32_16x16x32_bf16(kf0, qf0, z, 0, 0, 0);
            z = __builtin_amdgcn_mfma_f32_16x16x32_bf16(kf1, qf1, z, 0, 0, 0);
            st[cb] = z;
        }
        __builtin_amdgcn_s_setprio(0);

        float pv[4][4];
        float sum = 0.0f;
#pragma unroll
        for (int cb = 0; cb < 4; ++cb) {
            const int scb = cb * 16 + quad * 4;
#pragma unroll
            for (int r = 0; r < 4; ++r) {
                float e = exp2f(st[cb][r]);
                if (diag && (scb + r > wl)) e = 0.0f;
                pv[cb][r] = e;
                sum += e;
            }
        }
        sum += __shfl_xor(sum, 16);
        sum += __shfl_xor(sum, 32);
        l_st += sum;

        short4v pb[4];
#pragma unroll
        for (int cb = 0; cb < 4; ++cb) {
            uint lo_, hi_;
            asm("v_cvt_pk_bf16_f32 %0, %1, %2" : "=v"(lo_) : "v"(pv[cb][0]), "v"(pv[cb][1]));
            asm("v_cvt_pk_bf16_f32 %0, %1, %2" : "=v"(hi_) : "v"(pv[cb][2]), "v"(pv[cb][3]));
            union { uint u[2]; short4v s; } cvu;
            cvu.u[0] = lo_; cvu.u[1] = hi_;
            pb[cb] = cvu.s;
        }

        __builtin_amdgcn_s_setprio(1);
#pragma unroll
        for (int db = 0; db < 4; ++db) {
#pragma unroll
            for (int cb = 0; cb < 4; ++cb) {
                short4v vf = *(const short4v*)(vc + vbs[cb] + db * 1024);
                od[db] = __builtin_amdgcn_mfma_f32_16x16x16bf16_1k(vf, pb[cb], od[db], 0, 0, 0);
            }
        }
        __builtin_amdgcn_s_setprio(0);
        if (pref) __syncthreads();   // protect buffer reuse; last iter skips
    };

    for (int kt = 0; kt < dt; ++kt) step(kt, false, true);   // maskless main loop
    step(dt, true, false);                                    // peeled diagonal tile

    const float linv = 1.0f / l_st;
    ushort* orow = Og + (size_t)(bq + qt * 64 + wl) * 1024 + h * 64 + quad * 4;
#pragma unroll
    for (int db = 0; db < 4; ++db) {
        uint2 w;
        w.x = (uint)f2b(od[db][0] * linv) | ((uint)f2b(od[db][1] * linv) << 16);
        w.y = (uint)f2b(od[db][2] * linv) | ((uint)f2b(od[db][3] * linv) << 16);
        *(uint2*)(orow + db * 16) = w;
    }
}

extern "C" void kernel_launch(void* const* d_in, const int* in_sizes, int n_in,
                              void* d_out, int out_size, void* d_ws, size_t ws_size,
                              hipStream_t stream) {
    const float* x  = (const float*)d_in[0];
    const float* wq = (const float*)d_in[1];
    const float* wk = (const float*)d_in[2];
    const float* wv = (const float*)d_in[3];
    const float* wo = (const float*)d_in[4];
    const int* pos  = (const int*)d_in[5];

    const size_t NX = (size_t)4096 * 1024;
    const size_t NW = (size_t)1024 * 1024;

    ushort* q_ws  = (ushort*)d_ws;          // 8 MB each, 32 MiB total
    ushort* k_ws  = q_ws + NX;
    ushort* vt_ws = k_ws + NX;
    ushort* o_ws  = vt_ws + NX;
    // d_out (16 MB) doubles as bf16 scratch + rope table until the final GEMM
    ushort* xb  = (ushort*)d_out;           // 8 MB
    ushort* wqb = xb + NX;                  // 2 MB each
    ushort* wkb = wqb + NW;
    ushort* wvb = wkb + NW;
    float2* tab = (float2*)(wvb + NW);      // 512 KB

    cvt4_k<<<dim3(3840), 256, 0, stream>>>(x, wq, wk, wv, xb, wqb, wkb, wvb, pos, tab);
    gemm_qkv<<<dim3(512), 256, 0, stream>>>(xb, wqb, wkb, wvb, q_ws, k_ws, vt_ws, tab);
    attn_k<<<dim3(1024), 256, 0, stream>>>(q_ws, k_ws, vt_ws, o_ws);
    cvt_k<<<dim3(512), 256, 0, stream>>>(wo, q_ws, (int)NW);   // q_ws dead now
    gemm_o<<<dim3(512), 256, 0, stream>>>(o_ws, q_ws, (float*)d_out);
}

// Round 7
// 190.737 us; speedup vs baseline: 1.0538x; 1.0538x over previous
//
#include <hip/hip_runtime.h>

typedef __attribute__((ext_vector_type(8))) short short8;
typedef __attribute__((ext_vector_type(4))) short short4v;
typedef __attribute__((ext_vector_type(4))) float floatx4;

__device__ inline ushort f2b(float f) {
    union { uint i; float f; } c; c.f = f;
    uint i = c.i;
    uint r = (i + 0x7FFFu + ((i >> 16) & 1u)) >> 16;
    return (ushort)r;
}

__device__ __forceinline__ void load_lds16(const ushort* g, ushort* l) {
    __builtin_amdgcn_global_load_lds((const __attribute__((address_space(1))) void*)g,
                                     (__attribute__((address_space(3))) void*)l, 16, 0, 0);
}

// Fused fp32->bf16 conversion of x, wq, wk, wv + RoPE cos/sin table (one launch).
__global__ __launch_bounds__(256) void cvt4_k(const float* __restrict__ x,
                                              const float* __restrict__ wq,
                                              const float* __restrict__ wk,
                                              const float* __restrict__ wv,
                                              ushort* __restrict__ xb,
                                              ushort* __restrict__ wqb,
                                              ushort* __restrict__ wkb,
                                              ushort* __restrict__ wvb,
                                              const int* __restrict__ pos,
                                              float2* __restrict__ tab) {
    const int blk = blockIdx.x;
    if (blk >= 3584) {
        const int idx = (blk - 3584) * 256 + threadIdx.x;   // 0..65535
        const int s = idx >> 5, fi = idx & 31;
        const float inv = exp2f(-(float)fi * 0.41524101186092557f);
        const float ang = (float)pos[s] * inv;
        float sn, cs;
        sincosf(ang, &sn, &cs);
        tab[idx] = make_float2(cs, sn);
        return;
    }
    const float* in; ushort* out; int base;
    if (blk < 2048)      { in = x;  out = xb;  base = blk; }
    else if (blk < 2560) { in = wq; out = wqb; base = blk - 2048; }
    else if (blk < 3072) { in = wk; out = wkb; base = blk - 2560; }
    else                 { in = wv; out = wvb; base = blk - 3072; }
    const int i = (base * 256 + threadIdx.x) * 8;
    float4 f0 = *(const float4*)(in + i);
    float4 f1 = *(const float4*)(in + i + 4);
    ushort u[8] = {f2b(f0.x), f2b(f0.y), f2b(f0.z), f2b(f0.w),
                   f2b(f1.x), f2b(f1.y), f2b(f1.z), f2b(f1.w)};
    *(uint4*)(out + i) = *(const uint4*)u;
}

__global__ __launch_bounds__(256) void cvt_k(const float* __restrict__ in,
                                             ushort* __restrict__ out, int n) {
    const int i = (blockIdx.x * 256 + threadIdx.x) * 8;
    if (i >= n) return;
    float4 f0 = *(const float4*)(in + i);
    float4 f1 = *(const float4*)(in + i + 4);
    ushort u[8] = {f2b(f0.x), f2b(f0.y), f2b(f0.z), f2b(f0.w),
                   f2b(f1.x), f2b(f1.y), f2b(f1.z), f2b(f1.w)};
    *(uint4*)(out + i) = *(const uint4*)u;
}

// 128x128 GEMM body, K=1024, BK=32, EIGHT waves (2m x 4n of 64x32 each).
// Same verified 2-phase skeleton as the 4-wave version: double-buffered LDS,
// one __syncthreads per K-iter, identical chunk swizzle. Per-wave work halves
// (8 MFMA/iter, acc[4][2]) and staging is 2 load_lds16/thread -> more
// independent wave streams per CU (TLP) at unchanged traffic.
template <bool OUTF32>
__device__ __forceinline__ void gemm_body8(ushort* As, ushort* Bs,   // [2][4096] each
                                           const ushort* __restrict__ A,
                                           const ushort* __restrict__ B,
                                           void* __restrict__ C,
                                           int N, int m0, int n0,
                                           bool doRope, const float2* __restrict__ tab,
                                           float oscale) {
    const int tid = threadIdx.x;            // 0..511
    const int wave = tid >> 6, lane = tid & 63;
    const int quad = lane >> 4, l16 = lane & 15;
    const int wm = (wave >> 2) * 64, wn = (wave & 3) * 32;

    floatx4 acc[4][2] = {};

    // staging: A tile = 512 chunks of 16B, B tile = 512 chunks; thread tid
    // covers chunk tid of each. chunk c: row = c>>2, j_lds = c&3,
    // j_g = (j_lds - (row>>1)) & 3  (inverse of the read-side swizzle).
    const int rA = tid >> 2, jgA = ((tid & 3) - (rA >> 1)) & 3;
    const ushort* ga = A + (size_t)(m0 + rA) * 1024 + jgA * 8;
    const ushort* gb = B + (size_t)(n0 + rA) * 1024 + jgA * 8;

    load_lds16(ga, As + tid * 8);
    load_lds16(gb, Bs + tid * 8);
    __syncthreads();

    for (int kt = 0; kt < 32; ++kt) {
        const int cur = kt & 1;
        if (kt + 1 < 32) {
            const int nb = (cur ^ 1) * 4096;
            load_lds16(ga + (kt + 1) * 32, As + nb + tid * 8);
            load_lds16(gb + (kt + 1) * 32, Bs + nb + tid * 8);
        }
        const ushort* as = As + cur * 4096;
        const ushort* bs = Bs + cur * 4096;
        short8 af[4], bf[2];
#pragma unroll
        for (int i = 0; i < 4; ++i) {
            const int ra = wm + i * 16 + l16;
            af[i] = *(const short8*)(as + ra * 32 + (((quad + (ra >> 1)) & 3) << 3));
        }
#pragma unroll
        for (int j = 0; j < 2; ++j) {
            const int rb = wn + j * 16 + l16;
            bf[j] = *(const short8*)(bs + rb * 32 + (((quad + (rb >> 1)) & 3) << 3));
        }
#pragma unroll
        for (int mi = 0; mi < 4; ++mi)
#pragma unroll
            for (int ni = 0; ni < 2; ++ni)
                acc[mi][ni] = __builtin_amdgcn_mfma_f32_16x16x32_bf16(af[mi], bf[ni], acc[mi][ni], 0, 0, 0);
        __syncthreads();
    }
#pragma unroll
    for (int mi = 0; mi < 4; ++mi) {
        const int row = m0 + wm + mi * 16 + quad * 4;
#pragma unroll
        for (int ni = 0; ni < 2; ++ni) {
            const int col = n0 + wn + ni * 16 + l16;
            const int fi = ((wn + ni * 16 + l16) & 63) >> 1;
#pragma unroll
            for (int r = 0; r < 4; ++r) {
                float v = acc[mi][ni][r];
                if (doRope) {
                    const float other = __shfl_xor(v, 1);
                    const float2 cs = tab[((row + r) & 2047) * 32 + fi];
                    v = (col & 1) ? (other * cs.y + v * cs.x) : (v * cs.x - other * cs.y);
                }
                v *= oscale;
                if (OUTF32) ((float*)C)[(size_t)(row + r) * N + col] = v;
                else        ((ushort*)C)[(size_t)(row + r) * N + col] = f2b(v);
            }
        }
    }
}

// Fused Q/K/Vt GEMM: 768 blocks x 512 threads (8 waves). Same job split and
// tile map as the R4-verified kernel; only the wave decomposition changed.
// RoPE fused for Q,K; softmax scale folded into Q.
__global__ __launch_bounds__(512) void gemm_qkv(const ushort* __restrict__ xb,
                                                const ushort* __restrict__ wqb,
                                                const ushort* __restrict__ wkb,
                                                const ushort* __restrict__ wvb,
                                                ushort* __restrict__ q,
                                                ushort* __restrict__ k,
                                                ushort* __restrict__ vt,
                                                const float2* __restrict__ tab) {
    __shared__ __align__(16) ushort As[8192], Bs[8192];
    const int blk = blockIdx.x;
    const int job = blk >> 8, r = blk & 255;
    const ushort *A, *B;
    ushort* C;
    int N, m0, n0;
    bool rope;
    float osc;
    if (job == 0)      { A = xb;  B = wqb; C = q;  N = 1024; m0 = (r >> 3) * 128; n0 = (r & 7) * 128; rope = true;  osc = 0.18033688011112042f; }
    else if (job == 1) { A = xb;  B = wkb; C = k;  N = 1024; m0 = (r >> 3) * 128; n0 = (r & 7) * 128; rope = true;  osc = 1.0f; }
    else               { A = wvb; B = xb;  C = vt; N = 4096; m0 = (r & 7) * 128;  n0 = (r >> 3) * 128; rope = false; osc = 1.0f; }
    gemm_body8<false>(As, Bs, A, B, C, N, m0, n0, rope, tab, osc);
}

// Output projection: C fp32 = O[4096][1024] * wo[1024][1024]^T.
// R4-verified form: 128x64 tiles, 512 blocks = 2 blocks/CU, bf16 B via cvt_k.
__global__ __launch_bounds__(256) void gemm_o(const ushort* __restrict__ A,
                                              const ushort* __restrict__ B,
                                              float* __restrict__ C) {
    __shared__ __align__(16) ushort As[8192];   // 2 bufs x 128 rows x 32 cols
    __shared__ __align__(16) ushort Bs[4096];   // 2 bufs x  64 rows x 32 cols

    const int blk = blockIdx.x;
    const int m0 = (blk >> 4) * 128, n0 = (blk & 15) * 64;

    const int tid = threadIdx.x;
    const int wave = tid >> 6, lane = tid & 63;
    const int quad = lane >> 4, l16 = lane & 15;
    const int wm = (wave >> 1) * 64, wn = (wave & 1) * 32;

    floatx4 acc[4][2] = {};

    const int cA1 = tid, cA2 = tid + 256, cBc = tid;
    const int rA1 = cA1 >> 2, jg1 = ((cA1 & 3) - (rA1 >> 1)) & 3;
    const int rA2 = cA2 >> 2, jg2 = ((cA2 & 3) - (rA2 >> 1)) & 3;
    const int rBc = cBc >> 2, jgB = ((cBc & 3) - (rBc >> 1)) & 3;
    const ushort* ga1 = A + (size_t)(m0 + rA1) * 1024 + jg1 * 8;
    const ushort* ga2 = A + (size_t)(m0 + rA2) * 1024 + jg2 * 8;
    const ushort* gb1 = B + (size_t)(n0 + rBc) * 1024 + jgB * 8;

    load_lds16(ga1, As + cA1 * 8);
    load_lds16(ga2, As + cA2 * 8);
    load_lds16(gb1, Bs + cBc * 8);
    __syncthreads();

    for (int kt = 0; kt < 32; ++kt) {
        const int cur = kt & 1;
        if (kt + 1 < 32) {
            const int nbA = (cur ^ 1) * 4096;
            const int nbB = (cur ^ 1) * 2048;
            load_lds16(ga1 + (kt + 1) * 32, As + nbA + cA1 * 8);
            load_lds16(ga2 + (kt + 1) * 32, As + nbA + cA2 * 8);
            load_lds16(gb1 + (kt + 1) * 32, Bs + nbB + cBc * 8);
        }
        const ushort* as = As + cur * 4096;
        const ushort* bs = Bs + cur * 2048;
        short8 af[4], bf[2];
#pragma unroll
        for (int i = 0; i < 4; ++i) {
            const int ra = wm + i * 16 + l16;
            af[i] = *(const short8*)(as + ra * 32 + (((quad + (ra >> 1)) & 3) << 3));
        }
#pragma unroll
        for (int j = 0; j < 2; ++j) {
            const int rb = wn + j * 16 + l16;
            bf[j] = *(const short8*)(bs + rb * 32 + (((quad + (rb >> 1)) & 3) << 3));
        }
#pragma unroll
        for (int mi = 0; mi < 4; ++mi)
#pragma unroll
            for (int ni = 0; ni < 2; ++ni)
                acc[mi][ni] = __builtin_amdgcn_mfma_f32_16x16x32_bf16(af[mi], bf[ni], acc[mi][ni], 0, 0, 0);
        __syncthreads();
    }
#pragma unroll
    for (int mi = 0; mi < 4; ++mi) {
        const int row = m0 + wm + mi * 16 + quad * 4;
#pragma unroll
        for (int ni = 0; ni < 2; ++ni) {
            const int col = n0 + wn + ni * 16 + l16;
#pragma unroll
            for (int r = 0; r < 4; ++r)
                C[(size_t)(row + r) * 1024 + col] = acc[mi][ni][r];
        }
    }
}

// Causal flash attention. 1024 blocks: one 64-row q-tile each, heavy tiles
// first; 4 blocks/CU. Q pre-scaled by 0.125*log2(e), so P = exp2(S) directly.
// Diagonal k-tile peeled (maskless main loop). Verified structure.
__global__ __launch_bounds__(256, 4) void attn_k(const ushort* __restrict__ Qg,
                                                 const ushort* __restrict__ Kg,
                                                 const ushort* __restrict__ Vtg,
                                                 ushort* __restrict__ Og) {
    __shared__ __align__(16) ushort Ks[2][4096];   // [s][d] chunk-swizzled
    __shared__ __align__(16) ushort Vs[2][4096];   // [d][s] chunk-swizzled

    const int tid = threadIdx.x;
    const int wave = tid >> 6, lane = tid & 63;
    const int quad = lane >> 4, l16 = lane & 15;
    const int blk = blockIdx.x;
    const int bh = blk & 31;
    const int qt = 31 - (blk >> 5);                // heavy-first
    const int b = bh >> 4, h = bh & 15;
    const int bq = b * 2048;
    const int wl = wave * 16 + l16;                // q-row within 64-row tile
    const int nk = qt + 1, dt = nk - 1;

    const int cA = tid, cB = tid + 256;
    const int sA = cA >> 3, jA = ((cA & 7) - sA) & 7;
    const int sB = cB >> 3, jB = ((cB & 7) - sB) & 7;
    const ushort* kgA = Kg + (size_t)(bq + sA) * 1024 + h * 64 + jA * 8;
    const ushort* kgB = Kg + (size_t)(bq + sB) * 1024 + h * 64 + jB * 8;
    const ushort* vgA = Vtg + (size_t)(h * 64 + sA) * 4096 + bq + jA * 8;
    const ushort* vgB = Vtg + (size_t)(h * 64 + sB) * 4096 + bq + jB * 8;

    // kt-invariant LDS read offsets (ushort units)
    const int kb0 = l16 * 64 + (((quad + l16) & 7) << 3);
    const int kb1 = l16 * 64 + (((quad + 4 + l16) & 7) << 3);
    int vbs[4];
#pragma unroll
    for (int cb = 0; cb < 4; ++cb)
        vbs[cb] = l16 * 64 + (((cb * 2 + (quad >> 1) + l16) & 7) << 3) + (quad & 1) * 4;

    const ushort* qrow = Qg + (size_t)(bq + qt * 64 + wl) * 1024 + h * 64 + quad * 8;
    const short8 qf0 = *(const short8*)qrow;
    const short8 qf1 = *(const short8*)(qrow + 32);

    floatx4 od[4] = {};
    float l_st = 0.0f;

    load_lds16(kgA, &Ks[0][cA * 8]);
    load_lds16(kgB, &Ks[0][cB * 8]);
    load_lds16(vgA, &Vs[0][cA * 8]);
    load_lds16(vgB, &Vs[0][cB * 8]);
    __syncthreads();

    const ushort* kgA2 = kgA + 65536;
    const ushort* kgB2 = kgB + 65536;
    const ushort* vgA2 = vgA + 64;
    const ushort* vgB2 = vgB + 64;

    auto step = [&](int kt, bool diag, bool pref) {
        const int cur = kt & 1;
        if (pref) {
            const int nxt = cur ^ 1;
            load_lds16(kgA2, &Ks[nxt][cA * 8]);
            load_lds16(kgB2, &Ks[nxt][cB * 8]);
            load_lds16(vgA2, &Vs[nxt][cA * 8]);
            load_lds16(vgB2, &Vs[nxt][cB * 8]);
            kgA2 += 65536; kgB2 += 65536; vgA2 += 64; vgB2 += 64;
        }
        const ushort* kc = &Ks[cur][0];
        const ushort* vc = &Vs[cur][0];

        // S^T = K Q^T  (Q pre-scaled, st already in log2 domain)
        floatx4 st[4];
        __builtin_amdgcn_s_setprio(1);
#pragma unroll
        for (int cb = 0; cb < 4; ++cb) {
            short8 kf0 = *(const short8*)(kc + kb0 + cb * 1024);
            short8 kf1 = *(const short8*)(kc + kb1 + cb * 1024);
            floatx4 z = {};
            z = __builtin_amdgcn_mfma_f32_16x16x32_bf16(kf0, qf0, z, 0, 0, 0);
            z = __builtin_amdgcn_mfma_f32_16x16x32_bf16(kf1, qf1, z, 0, 0, 0);
            st[cb] = z;
        }
        __builtin_amdgcn_s_setprio(0);

        float pv[4][4];
        float sum = 0.0f;
#pragma unroll
        for (int cb = 0; cb < 4; ++cb) {
            const int scb = cb * 16 + quad * 4;
#pragma unroll
            for (int r = 0; r < 4; ++r) {
                float e = exp2f(st[cb][r]);
                if (diag && (scb + r > wl)) e = 0.0f;
                pv[cb][r] = e;
                sum += e;
            }
        }
        sum += __shfl_xor(sum, 16);
        sum += __shfl_xor(sum, 32);
        l_st += sum;

        short4v pb[4];
#pragma unroll
        for (int cb = 0; cb < 4; ++cb) {
            uint lo_, hi_;
            asm("v_cvt_pk_bf16_f32 %0, %1, %2" : "=v"(lo_) : "v"(pv[cb][0]), "v"(pv[cb][1]));
            asm("v_cvt_pk_bf16_f32 %0, %1, %2" : "=v"(hi_) : "v"(pv[cb][2]), "v"(pv[cb][3]));
            union { uint u[2]; short4v s; } cvu;
            cvu.u[0] = lo_; cvu.u[1] = hi_;
            pb[cb] = cvu.s;
        }

        __builtin_amdgcn_s_setprio(1);
#pragma unroll
        for (int db = 0; db < 4; ++db) {
#pragma unroll
            for (int cb = 0; cb < 4; ++cb) {
                short4v vf = *(const short4v*)(vc + vbs[cb] + db * 1024);
                od[db] = __builtin_amdgcn_mfma_f32_16x16x16bf16_1k(vf, pb[cb], od[db], 0, 0, 0);
            }
        }
        __builtin_amdgcn_s_setprio(0);
        if (pref) __syncthreads();   // protect buffer reuse; last iter skips
    };

    for (int kt = 0; kt < dt; ++kt) step(kt, false, true);   // maskless main loop
    step(dt, true, false);                                    // peeled diagonal tile

    const float linv = 1.0f / l_st;
    ushort* orow = Og + (size_t)(bq + qt * 64 + wl) * 1024 + h * 64 + quad * 4;
#pragma unroll
    for (int db = 0; db < 4; ++db) {
        uint2 w;
        w.x = (uint)f2b(od[db][0] * linv) | ((uint)f2b(od[db][1] * linv) << 16);
        w.y = (uint)f2b(od[db][2] * linv) | ((uint)f2b(od[db][3] * linv) << 16);
        *(uint2*)(orow + db * 16) = w;
    }
}

extern "C" void kernel_launch(void* const* d_in, const int* in_sizes, int n_in,
                              void* d_out, int out_size, void* d_ws, size_t ws_size,
                              hipStream_t stream) {
    const float* x  = (const float*)d_in[0];
    const float* wq = (const float*)d_in[1];
    const float* wk = (const float*)d_in[2];
    const float* wv = (const float*)d_in[3];
    const float* wo = (const float*)d_in[4];
    const int* pos  = (const int*)d_in[5];

    const size_t NX = (size_t)4096 * 1024;
    const size_t NW = (size_t)1024 * 1024;

    ushort* q_ws  = (ushort*)d_ws;          // 8 MB each, 32 MiB total
    ushort* k_ws  = q_ws + NX;
    ushort* vt_ws = k_ws + NX;
    ushort* o_ws  = vt_ws + NX;
    // d_out (16 MB) doubles as bf16 scratch + rope table until the final GEMM
    ushort* xb  = (ushort*)d_out;           // 8 MB
    ushort* wqb = xb + NX;                  // 2 MB each
    ushort* wkb = wqb + NW;
    ushort* wvb = wkb + NW;
    float2* tab = (float2*)(wvb + NW);      // 512 KB

    cvt4_k<<<dim3(3840), 256, 0, stream>>>(x, wq, wk, wv, xb, wqb, wkb, wvb, pos, tab);
    gemm_qkv<<<dim3(768), 512, 0, stream>>>(xb, wqb, wkb, wvb, q_ws, k_ws, vt_ws, tab);
    attn_k<<<dim3(1024), 256, 0, stream>>>(q_ws, k_ws, vt_ws, o_ws);
    cvt_k<<<dim3(512), 256, 0, stream>>>(wo, q_ws, (int)NW);   // q_ws dead now
    gemm_o<<<dim3(512), 256, 0, stream>>>(o_ws, q_ws, (float*)d_out);
}

// Round 8
// 189.947 us; speedup vs baseline: 1.0582x; 1.0042x over previous
//
#include <hip/hip_runtime.h>

typedef __attribute__((ext_vector_type(8))) short short8;
typedef __attribute__((ext_vector_type(4))) short short4v;
typedef __attribute__((ext_vector_type(4))) float floatx4;

__device__ inline ushort f2b(float f) {
    union { uint i; float f; } c; c.f = f;
    uint i = c.i;
    uint r = (i + 0x7FFFu + ((i >> 16) & 1u)) >> 16;
    return (ushort)r;
}

__device__ __forceinline__ void load_lds16(const ushort* g, ushort* l) {
    __builtin_amdgcn_global_load_lds((const __attribute__((address_space(1))) void*)g,
                                     (__attribute__((address_space(3))) void*)l, 16, 0, 0);
}

// Fused fp32->bf16 conversion of x, wq, wk, wv + RoPE cos/sin table (one launch).
__global__ __launch_bounds__(256) void cvt4_k(const float* __restrict__ x,
                                              const float* __restrict__ wq,
                                              const float* __restrict__ wk,
                                              const float* __restrict__ wv,
                                              ushort* __restrict__ xb,
                                              ushort* __restrict__ wqb,
                                              ushort* __restrict__ wkb,
                                              ushort* __restrict__ wvb,
                                              const int* __restrict__ pos,
                                              float2* __restrict__ tab) {
    const int blk = blockIdx.x;
    if (blk >= 3584) {
        const int idx = (blk - 3584) * 256 + threadIdx.x;   // 0..65535
        const int s = idx >> 5, fi = idx & 31;
        const float inv = exp2f(-(float)fi * 0.41524101186092557f);
        const float ang = (float)pos[s] * inv;
        float sn, cs;
        sincosf(ang, &sn, &cs);
        tab[idx] = make_float2(cs, sn);
        return;
    }
    const float* in; ushort* out; int base;
    if (blk < 2048)      { in = x;  out = xb;  base = blk; }
    else if (blk < 2560) { in = wq; out = wqb; base = blk - 2048; }
    else if (blk < 3072) { in = wk; out = wkb; base = blk - 2560; }
    else                 { in = wv; out = wvb; base = blk - 3072; }
    const int i = (base * 256 + threadIdx.x) * 8;
    float4 f0 = *(const float4*)(in + i);
    float4 f1 = *(const float4*)(in + i + 4);
    ushort u[8] = {f2b(f0.x), f2b(f0.y), f2b(f0.z), f2b(f0.w),
                   f2b(f1.x), f2b(f1.y), f2b(f1.z), f2b(f1.w)};
    *(uint4*)(out + i) = *(const uint4*)u;
}

__global__ __launch_bounds__(256) void cvt_k(const float* __restrict__ in,
                                             ushort* __restrict__ out, int n) {
    const int i = (blockIdx.x * 256 + threadIdx.x) * 8;
    if (i >= n) return;
    float4 f0 = *(const float4*)(in + i);
    float4 f1 = *(const float4*)(in + i + 4);
    ushort u[8] = {f2b(f0.x), f2b(f0.y), f2b(f0.z), f2b(f0.w),
                   f2b(f1.x), f2b(f1.y), f2b(f1.z), f2b(f1.w)};
    *(uint4*)(out + i) = *(const uint4*)u;
}

// 128x128 GEMM body, K=1024, BK=32, EIGHT waves (2m x 4n of 64x32 each).
// Verified 2-phase skeleton: double-buffered LDS, one __syncthreads per K-iter.
template <bool OUTF32>
__device__ __forceinline__ void gemm_body8(ushort* As, ushort* Bs,   // [2][4096] each
                                           const ushort* __restrict__ A,
                                           const ushort* __restrict__ B,
                                           void* __restrict__ C,
                                           int N, int m0, int n0,
                                           bool doRope, const float2* __restrict__ tab,
                                           float oscale) {
    const int tid = threadIdx.x;            // 0..511
    const int wave = tid >> 6, lane = tid & 63;
    const int quad = lane >> 4, l16 = lane & 15;
    const int wm = (wave >> 2) * 64, wn = (wave & 3) * 32;

    floatx4 acc[4][2] = {};

    const int rA = tid >> 2, jgA = ((tid & 3) - (rA >> 1)) & 3;
    const ushort* ga = A + (size_t)(m0 + rA) * 1024 + jgA * 8;
    const ushort* gb = B + (size_t)(n0 + rA) * 1024 + jgA * 8;

    load_lds16(ga, As + tid * 8);
    load_lds16(gb, Bs + tid * 8);
    __syncthreads();

    for (int kt = 0; kt < 32; ++kt) {
        const int cur = kt & 1;
        if (kt + 1 < 32) {
            const int nb = (cur ^ 1) * 4096;
            load_lds16(ga + (kt + 1) * 32, As + nb + tid * 8);
            load_lds16(gb + (kt + 1) * 32, Bs + nb + tid * 8);
        }
        const ushort* as = As + cur * 4096;
        const ushort* bs = Bs + cur * 4096;
        short8 af[4], bf[2];
#pragma unroll
        for (int i = 0; i < 4; ++i) {
            const int ra = wm + i * 16 + l16;
            af[i] = *(const short8*)(as + ra * 32 + (((quad + (ra >> 1)) & 3) << 3));
        }
#pragma unroll
        for (int j = 0; j < 2; ++j) {
            const int rb = wn + j * 16 + l16;
            bf[j] = *(const short8*)(bs + rb * 32 + (((quad + (rb >> 1)) & 3) << 3));
        }
#pragma unroll
        for (int mi = 0; mi < 4; ++mi)
#pragma unroll
            for (int ni = 0; ni < 2; ++ni)
                acc[mi][ni] = __builtin_amdgcn_mfma_f32_16x16x32_bf16(af[mi], bf[ni], acc[mi][ni], 0, 0, 0);
        __syncthreads();
    }
#pragma unroll
    for (int mi = 0; mi < 4; ++mi) {
        const int row = m0 + wm + mi * 16 + quad * 4;
#pragma unroll
        for (int ni = 0; ni < 2; ++ni) {
            const int col = n0 + wn + ni * 16 + l16;
            const int fi = ((wn + ni * 16 + l16) & 63) >> 1;
#pragma unroll
            for (int r = 0; r < 4; ++r) {
                float v = acc[mi][ni][r];
                if (doRope) {
                    const float other = __shfl_xor(v, 1);
                    const float2 cs = tab[((row + r) & 2047) * 32 + fi];
                    v = (col & 1) ? (other * cs.y + v * cs.x) : (v * cs.x - other * cs.y);
                }
                v *= oscale;
                if (OUTF32) ((float*)C)[(size_t)(row + r) * N + col] = v;
                else        ((ushort*)C)[(size_t)(row + r) * N + col] = f2b(v);
            }
        }
    }
}

// Fused Q/K/Vt GEMM: 768 blocks x 512 threads (8 waves). R7-verified.
__global__ __launch_bounds__(512) void gemm_qkv(const ushort* __restrict__ xb,
                                                const ushort* __restrict__ wqb,
                                                const ushort* __restrict__ wkb,
                                                const ushort* __restrict__ wvb,
                                                ushort* __restrict__ q,
                                                ushort* __restrict__ k,
                                                ushort* __restrict__ vt,
                                                const float2* __restrict__ tab) {
    __shared__ __align__(16) ushort As[8192], Bs[8192];
    const int blk = blockIdx.x;
    const int job = blk >> 8, r = blk & 255;
    const ushort *A, *B;
    ushort* C;
    int N, m0, n0;
    bool rope;
    float osc;
    if (job == 0)      { A = xb;  B = wqb; C = q;  N = 1024; m0 = (r >> 3) * 128; n0 = (r & 7) * 128; rope = true;  osc = 0.18033688011112042f; }
    else if (job == 1) { A = xb;  B = wkb; C = k;  N = 1024; m0 = (r >> 3) * 128; n0 = (r & 7) * 128; rope = true;  osc = 1.0f; }
    else               { A = wvb; B = xb;  C = vt; N = 4096; m0 = (r & 7) * 128;  n0 = (r >> 3) * 128; rope = false; osc = 1.0f; }
    gemm_body8<false>(As, Bs, A, B, C, N, m0, n0, rope, tab, osc);
}

// Output projection: C fp32 = O[4096][1024] * wo[1024][1024]^T.
// R4-verified form: 128x64 tiles, 512 blocks = 2 blocks/CU, bf16 B via cvt_k.
__global__ __launch_bounds__(256) void gemm_o(const ushort* __restrict__ A,
                                              const ushort* __restrict__ B,
                                              float* __restrict__ C) {
    __shared__ __align__(16) ushort As[8192];   // 2 bufs x 128 rows x 32 cols
    __shared__ __align__(16) ushort Bs[4096];   // 2 bufs x  64 rows x 32 cols

    const int blk = blockIdx.x;
    const int m0 = (blk >> 4) * 128, n0 = (blk & 15) * 64;

    const int tid = threadIdx.x;
    const int wave = tid >> 6, lane = tid & 63;
    const int quad = lane >> 4, l16 = lane & 15;
    const int wm = (wave >> 1) * 64, wn = (wave & 1) * 32;

    floatx4 acc[4][2] = {};

    const int cA1 = tid, cA2 = tid + 256, cBc = tid;
    const int rA1 = cA1 >> 2, jg1 = ((cA1 & 3) - (rA1 >> 1)) & 3;
    const int rA2 = cA2 >> 2, jg2 = ((cA2 & 3) - (rA2 >> 1)) & 3;
    const int rBc = cBc >> 2, jgB = ((cBc & 3) - (rBc >> 1)) & 3;
    const ushort* ga1 = A + (size_t)(m0 + rA1) * 1024 + jg1 * 8;
    const ushort* ga2 = A + (size_t)(m0 + rA2) * 1024 + jg2 * 8;
    const ushort* gb1 = B + (size_t)(n0 + rBc) * 1024 + jgB * 8;

    load_lds16(ga1, As + cA1 * 8);
    load_lds16(ga2, As + cA2 * 8);
    load_lds16(gb1, Bs + cBc * 8);
    __syncthreads();

    for (int kt = 0; kt < 32; ++kt) {
        const int cur = kt & 1;
        if (kt + 1 < 32) {
            const int nbA = (cur ^ 1) * 4096;
            const int nbB = (cur ^ 1) * 2048;
            load_lds16(ga1 + (kt + 1) * 32, As + nbA + cA1 * 8);
            load_lds16(ga2 + (kt + 1) * 32, As + nbA + cA2 * 8);
            load_lds16(gb1 + (kt + 1) * 32, Bs + nbB + cBc * 8);
        }
        const ushort* as = As + cur * 4096;
        const ushort* bs = Bs + cur * 2048;
        short8 af[4], bf[2];
#pragma unroll
        for (int i = 0; i < 4; ++i) {
            const int ra = wm + i * 16 + l16;
            af[i] = *(const short8*)(as + ra * 32 + (((quad + (ra >> 1)) & 3) << 3));
        }
#pragma unroll
        for (int j = 0; j < 2; ++j) {
            const int rb = wn + j * 16 + l16;
            bf[j] = *(const short8*)(bs + rb * 32 + (((quad + (rb >> 1)) & 3) << 3));
        }
#pragma unroll
        for (int mi = 0; mi < 4; ++mi)
#pragma unroll
            for (int ni = 0; ni < 2; ++ni)
                acc[mi][ni] = __builtin_amdgcn_mfma_f32_16x16x32_bf16(af[mi], bf[ni], acc[mi][ni], 0, 0, 0);
        __syncthreads();
    }
#pragma unroll
    for (int mi = 0; mi < 4; ++mi) {
        const int row = m0 + wm + mi * 16 + quad * 4;
#pragma unroll
        for (int ni = 0; ni < 2; ++ni) {
            const int col = n0 + wn + ni * 16 + l16;
#pragma unroll
            for (int r = 0; r < 4; ++r)
                C[(size_t)(row + r) * 1024 + col] = acc[mi][ni][r];
        }
    }
}

// Causal flash attention. 1024 blocks, all co-resident (4/CU). BALANCED qt map:
// the dispatcher assigns blocks to CUs on a 256-block cycle, so CU c runs
// blocks {c, c+256, c+512, c+768}. qt chosen so every CU's 4 blocks sum to
// nk = 66 steps (was 52..80 with the linear map -> ~35% drain imbalance).
//   t = (blk&255)>>5, g = blk>>8:  qt = {31-t, 23-t, t, 8+t}[g]
// Covers each (bh, qt) exactly once. Kernel body identical to R7 winner.
__global__ __launch_bounds__(256, 4) void attn_k(const ushort* __restrict__ Qg,
                                                 const ushort* __restrict__ Kg,
                                                 const ushort* __restrict__ Vtg,
                                                 ushort* __restrict__ Og) {
    __shared__ __align__(16) ushort Ks[2][4096];   // [s][d] chunk-swizzled
    __shared__ __align__(16) ushort Vs[2][4096];   // [d][s] chunk-swizzled

    const int tid = threadIdx.x;
    const int wave = tid >> 6, lane = tid & 63;
    const int quad = lane >> 4, l16 = lane & 15;
    const int blk = blockIdx.x;
    const int g = blk >> 8, rem = blk & 255;
    const int t = rem >> 5, bh = rem & 31;
    int qt;
    if (g == 0)      qt = 31 - t;
    else if (g == 1) qt = 23 - t;
    else if (g == 2) qt = t;
    else             qt = 8 + t;
    const int b = bh >> 4, h = bh & 15;
    const int bq = b * 2048;
    const int wl = wave * 16 + l16;                // q-row within 64-row tile
    const int nk = qt + 1, dt = nk - 1;

    const int cA = tid, cB = tid + 256;
    const int sA = cA >> 3, jA = ((cA & 7) - sA) & 7;
    const int sB = cB >> 3, jB = ((cB & 7) - sB) & 7;
    const ushort* kgA = Kg + (size_t)(bq + sA) * 1024 + h * 64 + jA * 8;
    const ushort* kgB = Kg + (size_t)(bq + sB) * 1024 + h * 64 + jB * 8;
    const ushort* vgA = Vtg + (size_t)(h * 64 + sA) * 4096 + bq + jA * 8;
    const ushort* vgB = Vtg + (size_t)(h * 64 + sB) * 4096 + bq + jB * 8;

    // kt-invariant LDS read offsets (ushort units)
    const int kb0 = l16 * 64 + (((quad + l16) & 7) << 3);
    const int kb1 = l16 * 64 + (((quad + 4 + l16) & 7) << 3);
    int vbs[4];
#pragma unroll
    for (int cb = 0; cb < 4; ++cb)
        vbs[cb] = l16 * 64 + (((cb * 2 + (quad >> 1) + l16) & 7) << 3) + (quad & 1) * 4;

    const ushort* qrow = Qg + (size_t)(bq + qt * 64 + wl) * 1024 + h * 64 + quad * 8;
    const short8 qf0 = *(const short8*)qrow;
    const short8 qf1 = *(const short8*)(qrow + 32);

    floatx4 od[4] = {};
    float l_st = 0.0f;

    load_lds16(kgA, &Ks[0][cA * 8]);
    load_lds16(kgB, &Ks[0][cB * 8]);
    load_lds16(vgA, &Vs[0][cA * 8]);
    load_lds16(vgB, &Vs[0][cB * 8]);
    __syncthreads();

    const ushort* kgA2 = kgA + 65536;
    const ushort* kgB2 = kgB + 65536;
    const ushort* vgA2 = vgA + 64;
    const ushort* vgB2 = vgB + 64;

    auto step = [&](int kt, bool diag, bool pref) {
        const int cur = kt & 1;
        if (pref) {
            const int nxt = cur ^ 1;
            load_lds16(kgA2, &Ks[nxt][cA * 8]);
            load_lds16(kgB2, &Ks[nxt][cB * 8]);
            load_lds16(vgA2, &Vs[nxt][cA * 8]);
            load_lds16(vgB2, &Vs[nxt][cB * 8]);
            kgA2 += 65536; kgB2 += 65536; vgA2 += 64; vgB2 += 64;
        }
        const ushort* kc = &Ks[cur][0];
        const ushort* vc = &Vs[cur][0];

        // S^T = K Q^T  (Q pre-scaled, st already in log2 domain)
        floatx4 st[4];
        __builtin_amdgcn_s_setprio(1);
#pragma unroll
        for (int cb = 0; cb < 4; ++cb) {
            short8 kf0 = *(const short8*)(kc + kb0 + cb * 1024);
            short8 kf1 = *(const short8*)(kc + kb1 + cb * 1024);
            floatx4 z = {};
            z = __builtin_amdgcn_mfma_f32_16x16x32_bf16(kf0, qf0, z, 0, 0, 0);
            z = __builtin_amdgcn_mfma_f32_16x16x32_bf16(kf1, qf1, z, 0, 0, 0);
            st[cb] = z;
        }
        __builtin_amdgcn_s_setprio(0);

        float pv[4][4];
        float sum = 0.0f;
#pragma unroll
        for (int cb = 0; cb < 4; ++cb) {
            const int scb = cb * 16 + quad * 4;
#pragma unroll
            for (int r = 0; r < 4; ++r) {
                float e = exp2f(st[cb][r]);
                if (diag && (scb + r > wl)) e = 0.0f;
                pv[cb][r] = e;
                sum += e;
            }
        }
        sum += __shfl_xor(sum, 16);
        sum += __shfl_xor(sum, 32);
        l_st += sum;

        short4v pb[4];
#pragma unroll
        for (int cb = 0; cb < 4; ++cb) {
            uint lo_, hi_;
            asm("v_cvt_pk_bf16_f32 %0, %1, %2" : "=v"(lo_) : "v"(pv[cb][0]), "v"(pv[cb][1]));
            asm("v_cvt_pk_bf16_f32 %0, %1, %2" : "=v"(hi_) : "v"(pv[cb][2]), "v"(pv[cb][3]));
            union { uint u[2]; short4v s; } cvu;
            cvu.u[0] = lo_; cvu.u[1] = hi_;
            pb[cb] = cvu.s;
        }

        __builtin_amdgcn_s_setprio(1);
#pragma unroll
        for (int db = 0; db < 4; ++db) {
#pragma unroll
            for (int cb = 0; cb < 4; ++cb) {
                short4v vf = *(const short4v*)(vc + vbs[cb] + db * 1024);
                od[db] = __builtin_amdgcn_mfma_f32_16x16x16bf16_1k(vf, pb[cb], od[db], 0, 0, 0);
            }
        }
        __builtin_amdgcn_s_setprio(0);
        if (pref) __syncthreads();   // protect buffer reuse; last iter skips
    };

    for (int kt = 0; kt < dt; ++kt) step(kt, false, true);   // maskless main loop
    step(dt, true, false);                                    // peeled diagonal tile

    const float linv = 1.0f / l_st;
    ushort* orow = Og + (size_t)(bq + qt * 64 + wl) * 1024 + h * 64 + quad * 4;
#pragma unroll
    for (int db = 0; db < 4; ++db) {
        uint2 w;
        w.x = (uint)f2b(od[db][0] * linv) | ((uint)f2b(od[db][1] * linv) << 16);
        w.y = (uint)f2b(od[db][2] * linv) | ((uint)f2b(od[db][3] * linv) << 16);
        *(uint2*)(orow + db * 16) = w;
    }
}

extern "C" void kernel_launch(void* const* d_in, const int* in_sizes, int n_in,
                              void* d_out, int out_size, void* d_ws, size_t ws_size,
                              hipStream_t stream) {
    const float* x  = (const float*)d_in[0];
    const float* wq = (const float*)d_in[1];
    const float* wk = (const float*)d_in[2];
    const float* wv = (const float*)d_in[3];
    const float* wo = (const float*)d_in[4];
    const int* pos  = (const int*)d_in[5];

    const size_t NX = (size_t)4096 * 1024;
    const size_t NW = (size_t)1024 * 1024;

    ushort* q_ws  = (ushort*)d_ws;          // 8 MB each, 32 MiB total
    ushort* k_ws  = q_ws + NX;
    ushort* vt_ws = k_ws + NX;
    ushort* o_ws  = vt_ws + NX;
    // d_out (16 MB) doubles as bf16 scratch + rope table until the final GEMM
    ushort* xb  = (ushort*)d_out;           // 8 MB
    ushort* wqb = xb + NX;                  // 2 MB each
    ushort* wkb = wqb + NW;
    ushort* wvb = wkb + NW;
    float2* tab = (float2*)(wvb + NW);      // 512 KB

    cvt4_k<<<dim3(3840), 256, 0, stream>>>(x, wq, wk, wv, xb, wqb, wkb, wvb, pos, tab);
    gemm_qkv<<<dim3(768), 512, 0, stream>>>(xb, wqb, wkb, wvb, q_ws, k_ws, vt_ws, tab);
    attn_k<<<dim3(1024), 256, 0, stream>>>(q_ws, k_ws, vt_ws, o_ws);
    cvt_k<<<dim3(512), 256, 0, stream>>>(wo, q_ws, (int)NW);   // q_ws dead now
    gemm_o<<<dim3(512), 256, 0, stream>>>(o_ws, q_ws, (float*)d_out);
}